// Round 6
// baseline (1112.580 us; speedup 1.0000x reference)
//
#include <hip/hip_runtime.h>

#define Hdim  1024
#define Tdim  2048
#define Bdim  4
#define HUdim 4096
#define Mrows (Bdim*Tdim)   // 8192
#define CHUNK 2048          // HU processed in HUdim/CHUNK slices
#define NCH   (HUdim/CHUNK) // 2
#define NSEG  16            // T-segments for parallel scan
#define SEGL  (Tdim/NSEG)   // 128
#define SCHUNK 16

typedef __bf16 bf16;
typedef __bf16 bf16x8 __attribute__((ext_vector_type(8)));
typedef float  floatx4 __attribute__((ext_vector_type(4)));

__device__ __forceinline__ bf16 f2bf(float x) { return (bf16)x; }

// ---------------- fused weight transpose + f32->bf16 convert (all 7 weights) ----------------
// each region: src [K,N] row-major f32 -> dst [N,K] row-major bf16; 64x64 tiles
__global__ __launch_bounds__(256) void wconv_all(
    const float* __restrict__ s0, const float* __restrict__ s1, const float* __restrict__ s2,
    const float* __restrict__ s3, const float* __restrict__ s4, const float* __restrict__ s5,
    const float* __restrict__ s6,
    bf16* d0, bf16* d1, bf16* d2, bf16* d3, bf16* d4, bf16* d5, bf16* d6) {
  __shared__ float tile[64][65];
  int bid = blockIdx.x;
  const float* src; bf16* dst; int K, N, local;
  if (bid < 1024)      { src = s0; dst = d0; K = Hdim;  N = HUdim; local = bid; }
  else if (bid < 2048) { src = s1; dst = d1; K = Hdim;  N = HUdim; local = bid - 1024; }
  else if (bid < 3072) { src = s2; dst = d2; K = Hdim;  N = HUdim; local = bid - 2048; }
  else if (bid < 4096) { src = s3; dst = d3; K = HUdim; N = Hdim;  local = bid - 3072; }
  else if (bid < 5120) { src = s4; dst = d4; K = Hdim;  N = HUdim; local = bid - 4096; }
  else if (bid < 6144) { src = s5; dst = d5; K = HUdim; N = Hdim;  local = bid - 5120; }
  else                 { src = s6; dst = d6; K = Hdim;  N = Hdim;  local = bid - 6144; }
  const int nt = N >> 6;
  const int n0 = (local % nt) * 64, k0 = (local / nt) * 64;
  const int tr = threadIdx.x >> 6;   // 0..3
  const int tc = threadIdx.x & 63;
#pragma unroll
  for (int j = 0; j < 16; j++) {
    int r = j * 4 + tr;
    tile[r][tc] = src[(size_t)(k0 + r) * N + n0 + tc];
  }
  __syncthreads();
#pragma unroll
  for (int j = 0; j < 16; j++) {
    int r = j * 4 + tr;
    dst[(size_t)(n0 + r) * K + k0 + tc] = f2bf(tile[tc][r]);
  }
}

// ---------------- block reduction helper (256 threads, 4 values) ----------------
__device__ __forceinline__ void block_reduce4(float v[4], float* sm) {
#pragma unroll
  for (int off = 32; off > 0; off >>= 1) {
#pragma unroll
    for (int i = 0; i < 4; i++) v[i] += __shfl_down(v[i], off, 64);
  }
  const int w = threadIdx.x >> 6;
  if ((threadIdx.x & 63) == 0) {
#pragma unroll
    for (int i = 0; i < 4; i++) sm[w * 4 + i] = v[i];
  }
  __syncthreads();
#pragma unroll
  for (int i = 0; i < 4; i++) v[i] = sm[i] + sm[4 + i] + sm[8 + i] + sm[12 + i];
  __syncthreads();
}

// ---------------- ln0 + pre-LN + shift + TM mixes ----------------
__global__ __launch_bounds__(256) void ln_mix_tm(
    const float* __restrict__ x,
    const float* __restrict__ g0, const float* __restrict__ b0,
    const float* __restrict__ g1, const float* __restrict__ b1,
    const float* __restrict__ mk, const float* __restrict__ mv, const float* __restrict__ mr,
    float* __restrict__ x0, bf16* __restrict__ xk, bf16* __restrict__ xv, bf16* __restrict__ xr) {
  __shared__ float sm[16];
  const int bid = blockIdx.x;
  const int t = bid & (Tdim - 1);
  const int tid = threadIdx.x;
  const bool havep = (t > 0);
  const float hp = havep ? 1.f : 0.f;
  const float* rowc = x + (size_t)bid * Hdim;
  const float* rowp = havep ? (rowc - Hdim) : rowc;  // always in-bounds

  float c[4], p[4];
#pragma unroll
  for (int j = 0; j < 4; j++) c[j] = rowc[tid * 4 + j];
#pragma unroll
  for (int j = 0; j < 4; j++) p[j] = rowp[tid * 4 + j] * hp;

  float red[4] = {0.f, 0.f, 0.f, 0.f};
#pragma unroll
  for (int j = 0; j < 4; j++) { red[0] += c[j]; red[1] += c[j]*c[j]; red[2] += p[j]; red[3] += p[j]*p[j]; }
  block_reduce4(red, sm);
  const float inv = 1.f / Hdim;
  float mc = red[0]*inv, vc = red[1]*inv - mc*mc;
  float mp = red[2]*inv, vp = red[3]*inv - mp*mp;
  float sc = rsqrtf(vc + 1e-5f), sp = rsqrtf(vp + 1e-5f);

  float yc[4], yp[4];
#pragma unroll
  for (int j = 0; j < 4; j++) {
    int i = tid * 4 + j;
    yc[j] = (c[j] - mc) * sc * g0[i] + b0[i];
    yp[j] = ((p[j] - mp) * sp * g0[i] + b0[i]) * hp;
    x0[(size_t)bid * Hdim + i] = yc[j];
  }

  float r2[4] = {0.f, 0.f, 0.f, 0.f};
#pragma unroll
  for (int j = 0; j < 4; j++) { r2[0] += yc[j]; r2[1] += yc[j]*yc[j]; r2[2] += yp[j]; r2[3] += yp[j]*yp[j]; }
  block_reduce4(r2, sm);
  float mc2 = r2[0]*inv, vc2 = r2[1]*inv - mc2*mc2;
  float mp2 = r2[2]*inv, vp2 = r2[3]*inv - mp2*mp2;
  float sc2 = rsqrtf(vc2 + 1e-5f), sp2 = rsqrtf(vp2 + 1e-5f);

#pragma unroll
  for (int j = 0; j < 4; j++) {
    int i = tid * 4 + j;
    float xnc = (yc[j] - mc2) * sc2 * g1[i] + b1[i];
    float xnp = ((yp[j] - mp2) * sp2 * g1[i] + b1[i]) * hp;
    size_t o = (size_t)bid * Hdim + i;
    float a;
    a = mk[i]; xk[o] = f2bf(xnc * a + xnp * (1.f - a));
    a = mv[i]; xv[o] = f2bf(xnc * a + xnp * (1.f - a));
    a = mr[i]; xr[o] = f2bf(xnc * a + xnp * (1.f - a));
  }
}

// ---------------- post-LN + shift + CM mixes ----------------
__global__ __launch_bounds__(256) void ln_mix_cm(
    const float* __restrict__ xin,
    const float* __restrict__ g, const float* __restrict__ bb,
    const float* __restrict__ mk, const float* __restrict__ mr,
    bf16* __restrict__ xk, bf16* __restrict__ xr) {
  __shared__ float sm[16];
  const int bid = blockIdx.x;
  const int t = bid & (Tdim - 1);
  const int tid = threadIdx.x;
  const bool havep = (t > 0);
  const float hp = havep ? 1.f : 0.f;
  const float* rowc = xin + (size_t)bid * Hdim;
  const float* rowp = havep ? (rowc - Hdim) : rowc;

  float c[4], p[4];
#pragma unroll
  for (int j = 0; j < 4; j++) c[j] = rowc[tid * 4 + j];
#pragma unroll
  for (int j = 0; j < 4; j++) p[j] = rowp[tid * 4 + j] * hp;

  float red[4] = {0.f, 0.f, 0.f, 0.f};
#pragma unroll
  for (int j = 0; j < 4; j++) { red[0] += c[j]; red[1] += c[j]*c[j]; red[2] += p[j]; red[3] += p[j]*p[j]; }
  block_reduce4(red, sm);
  const float inv = 1.f / Hdim;
  float mc = red[0]*inv, vc = red[1]*inv - mc*mc;
  float mp = red[2]*inv, vp = red[3]*inv - mp*mp;
  float sc = rsqrtf(vc + 1e-5f), sp = rsqrtf(vp + 1e-5f);

#pragma unroll
  for (int j = 0; j < 4; j++) {
    int i = tid * 4 + j;
    float xnc = (c[j] - mc) * sc * g[i] + bb[i];
    float xnp = ((p[j] - mp) * sp * g[i] + bb[i]) * hp;
    size_t o = (size_t)bid * Hdim + i;
    float a;
    a = mk[i]; xk[o] = f2bf(xnc * a + xnp * (1.f - a));
    a = mr[i]; xr[o] = f2bf(xnc * a + xnp * (1.f - a));
  }
}

// ---------------- WKV parallel scan: pass A (per-segment end states) ----------------
__global__ __launch_bounds__(64) void wkv_part(
    const bf16* __restrict__ Kb, const bf16* __restrict__ Vb,
    float* __restrict__ stK, float* __restrict__ stKV,
    const float* __restrict__ tdec) {
  const int seg = blockIdx.x & (NSEG - 1);
  const int rest = blockIdx.x >> 4;       // b*32 + g
  const int b = rest >> 5, g = rest & 31;
  const int c = (g << 6) + threadIdx.x;
  const float decay = __expf(-__expf(tdec[c]));
  size_t base = ((size_t)b * Tdim + (size_t)seg * SEGL) * CHUNK + c;
  float sk = 0.f, skv = 0.f;
  for (int t0 = 0; t0 < SEGL; t0 += SCHUNK) {
    float kk[SCHUNK], vv[SCHUNK];
#pragma unroll
    for (int j = 0; j < SCHUNK; j++) {
      size_t idx = base + (size_t)(t0 + j) * CHUNK;
      kk[j] = (float)Kb[idx];
      vv[j] = (float)Vb[idx];
    }
#pragma unroll
    for (int j = 0; j < SCHUNK; j++) {
      float kvt = kk[j] * vv[j];
      sk  = fmaf(decay, sk, kk[j]);
      skv = fmaf(decay, skv, kvt);
    }
  }
  size_t so = ((size_t)seg * Bdim + b) * CHUNK + c;
  stK[so]  = sk;
  stKV[so] = skv;
}

// ---------------- WKV parallel scan: pass B (fold carry, emit P) ----------------
__global__ __launch_bounds__(64) void wkv_emit(
    const bf16* __restrict__ Kb, const bf16* __restrict__ Vb,
    const bf16* SRb, bf16* Pb,   // SRb/Pb alias: per-element read-before-write
    const float* __restrict__ stK, const float* __restrict__ stKV,
    const float* __restrict__ tdec, const float* __restrict__ tfst) {
  const int seg = blockIdx.x & (NSEG - 1);
  const int rest = blockIdx.x >> 4;
  const int b = rest >> 5, g = rest & 31;
  const int c = (g << 6) + threadIdx.x;
  const float ed = __expf(tdec[c]);
  const float decay = __expf(-ed);
  const float dfac  = __expf(-ed * (float)SEGL);   // decay^SEGL, exact closed form
  const float first = __expf(tfst[c]);

  float sk = 0.f, skv = 0.f;
  for (int j = 0; j < seg; j++) {
    size_t so = ((size_t)j * Bdim + b) * CHUNK + c;
    sk  = fmaf(dfac, sk, stK[so]);
    skv = fmaf(dfac, skv, stKV[so]);
  }

  size_t base = ((size_t)b * Tdim + (size_t)seg * SEGL) * CHUNK + c;
  for (int t0 = 0; t0 < SEGL; t0 += SCHUNK) {
    float kk[SCHUNK], vv[SCHUNK], rr[SCHUNK];
#pragma unroll
    for (int j = 0; j < SCHUNK; j++) {
      size_t idx = base + (size_t)(t0 + j) * CHUNK;
      kk[j] = (float)Kb[idx];
      vv[j] = (float)Vb[idx];
      rr[j] = (float)SRb[idx];
    }
#pragma unroll
    for (int j = 0; j < SCHUNK; j++) {
      size_t idx = base + (size_t)(t0 + j) * CHUNK;
      float kvt = kk[j] * vv[j];
      float wk  = fmaf(first, kk[j], sk) + 1e-8f;
      float wkv = fmaf(first, kvt, skv);
      Pb[idx] = f2bf(rr[j] * wkv * __builtin_amdgcn_rcpf(wk));
      sk  = fmaf(decay, sk, kk[j]);
      skv = fmaf(decay, skv, kvt);
    }
  }
}

// ---------------- MFMA GEMM core (BK=64: two 128x32 sub-tiles per barrier) ----------------
__device__ __forceinline__ void gld_lds(const bf16* g, bf16* l) {
  __builtin_amdgcn_global_load_lds(
      (const __attribute__((address_space(1))) void*)(g),
      (__attribute__((address_space(3))) void*)(l),
      16, 0, 0);
}

// XCD-aware swizzle: xcd=s%8 owns m-band [xcd*gm/8,...); n in groups of 2, m fastest.
__device__ __forceinline__ void swz(int s, int gm, int& m_t, int& n_t) {
  const int mpx  = gm >> 3;        // gm % 8 == 0 at all call sites
  const int xcd  = s & 7;
  const int ss   = s >> 3;
  const int pass = mpx << 1;
  const int ng   = ss / pass;
  const int rem  = ss - ng * pass;
  m_t = xcd * mpx + (rem >> 1);
  n_t = (ng << 1) + (rem & 1);
}

// As/Bs: 2 sub-tiles of 128x32 each (8192 bf16 = 16 KB per matrix)
__device__ __forceinline__ void mm_core64(
    const bf16* A, const bf16* Bt, int lda, int ldb, int K,
    long m0, long n0, int wv, int lane, int wm, int wn,
    bf16* As, bf16* Bs, floatx4 acc[4][4]) {
  const int srow = wv * 32 + (lane >> 2);
  const int scol = (lane & 3) * 8;
  const bf16* gA = A + (m0 + srow) * (long)lda + scol;
  const bf16* gB = Bt + (n0 + srow) * (long)ldb + scol;
  const long skipA = 16L * lda;
  const long skipB = 16L * ldb;
  bf16* lA = As + wv * 1024;
  bf16* lB = Bs + wv * 1024;
  const bf16* fa = As + ((wm * 64) + (lane & 15)) * 32 + (lane >> 4) * 8;
  const bf16* fb = Bs + ((wn * 64) + (lane & 15)) * 32 + (lane >> 4) * 8;

  const int ksteps = K >> 6;
  for (int kt = 0; kt < ksteps; ++kt) {
    __syncthreads();
    gld_lds(gA, lA);             gld_lds(gA + skipA, lA + 512);
    gld_lds(gA + 32, lA + 4096); gld_lds(gA + 32 + skipA, lA + 4096 + 512);
    gld_lds(gB, lB);             gld_lds(gB + skipB, lB + 512);
    gld_lds(gB + 32, lB + 4096); gld_lds(gB + 32 + skipB, lB + 4096 + 512);
    gA += 64; gB += 64;
    __syncthreads();
#pragma unroll
    for (int s = 0; s < 2; s++) {
      bf16x8 af[4], bfr[4];
#pragma unroll
      for (int i = 0; i < 4; i++) {
        af[i]  = *(const bf16x8*)(fa + s * 4096 + i * 512);
        bfr[i] = *(const bf16x8*)(fb + s * 4096 + i * 512);
      }
#pragma unroll
      for (int mt = 0; mt < 4; mt++)
#pragma unroll
        for (int nt = 0; nt < 4; nt++)
          acc[mt][nt] = __builtin_amdgcn_mfma_f32_16x16x32_bf16(af[mt], bfr[nt], acc[mt][nt], 0, 0, 0);
    }
  }
}

enum { E_EXP = 0, E_BF16 = 1, E_SIG = 2, E_ATOMIC = 3, E_SILU = 4, E_F32 = 5, E_SIGADD2 = 6 };

// SPLITK: grid = SPLITK*gm*gn; slice ks handles A/Bt columns [ks*K, (ks+1)*K)
template <int EPI, int SPLITK>
__global__ __launch_bounds__(256) void gemm_bt(
    const bf16* __restrict__ A, const bf16* __restrict__ Bt,
    void* Cout, const void* aux1, const void* aux2,
    int lda, int ldb, int ldc, int K, int gm, int gn) {
  __shared__ __align__(16) bf16 As[2 * 128 * 32];
  __shared__ __align__(16) bf16 Bs[2 * 128 * 32];
  const int tid = threadIdx.x;
  const int lane = tid & 63;
  const int wv = tid >> 6;
  const int wm = wv >> 1, wn = wv & 1;
  int s = blockIdx.x;
  if constexpr (SPLITK > 1) {
    const int per = gm * gn;
    const int ks = s / per;
    s -= ks * per;
    A  += (long)ks * K;
    Bt += (long)ks * K;
  }
  int m_t, n_t;
  swz(s, gm, m_t, n_t);
  const long m0 = (long)m_t * 128;
  const long n0 = (long)n_t * 128;

  floatx4 acc[4][4];
#pragma unroll
  for (int i = 0; i < 4; i++)
#pragma unroll
    for (int j = 0; j < 4; j++) acc[i][j] = (floatx4){0.f, 0.f, 0.f, 0.f};

  mm_core64(A, Bt, lda, ldb, K, m0, n0, wv, lane, wm, wn, As, Bs, acc);

  const int r0 = wm * 64 + ((lane >> 4) << 2);
  const int c0 = wn * 64 + (lane & 15);
#pragma unroll
  for (int mt = 0; mt < 4; mt++) {
#pragma unroll
    for (int i = 0; i < 4; i++) {
      long r = m0 + r0 + mt * 16 + i;
      long bidx = r * (long)ldc + n0 + c0;
#pragma unroll
      for (int nt = 0; nt < 4; nt++) {
        long idx = bidx + nt * 16;
        float v = acc[mt][nt][i];
        if constexpr (EPI == E_EXP) {
          ((bf16*)Cout)[idx] = f2bf(__expf(fminf(v, 60.f)));
        } else if constexpr (EPI == E_BF16) {
          ((bf16*)Cout)[idx] = f2bf(v);
        } else if constexpr (EPI == E_SIG) {
          ((bf16*)Cout)[idx] = f2bf(1.f / (1.f + __expf(-v)));
        } else if constexpr (EPI == E_ATOMIC) {
          atomicAdd((float*)Cout + idx, v);
        } else if constexpr (EPI == E_SILU) {
          ((bf16*)Cout)[idx] = f2bf(v / (1.f + __expf(-v)));
        } else if constexpr (EPI == E_F32) {
          ((float*)Cout)[idx] = v;
        } else {  // E_SIGADD2
          float a1 = ((const float*)aux1)[idx];
          float a2 = ((const float*)aux2)[idx];
          ((float*)Cout)[idx] = a1 + 1.f / (1.f + __expf(-v)) + a2;
        }
      }
    }
  }
}

// ---------------- fused K/V/R projection: 3 GEMMs in one launch ----------------
__global__ __launch_bounds__(256) void proj3(
    const bf16* __restrict__ xk, const bf16* __restrict__ xv, const bf16* __restrict__ xr,
    const bf16* __restrict__ Wk, const bf16* __restrict__ Wv, const bf16* __restrict__ Wr,
    bf16* Kc, bf16* Vc, bf16* SRc, int gm, int gn) {
  __shared__ __align__(16) bf16 As[2 * 128 * 32];
  __shared__ __align__(16) bf16 Bs[2 * 128 * 32];
  const int per = gm * gn;
  const int sub = blockIdx.x / per;          // 0:K 1:V 2:R
  const int s   = blockIdx.x - sub * per;
  const int tid = threadIdx.x;
  const int lane = tid & 63;
  const int wv = tid >> 6;
  const int wm = wv >> 1, wn = wv & 1;
  int m_t, n_t;
  swz(s, gm, m_t, n_t);
  const long m0 = (long)m_t * 128;
  const long n0 = (long)n_t * 128;

  const bf16* A  = (sub == 0) ? xk : (sub == 1) ? xv : xr;
  const bf16* Bt = (sub == 0) ? Wk : (sub == 1) ? Wv : Wr;
  bf16*       C  = (sub == 0) ? Kc : (sub == 1) ? Vc : SRc;

  floatx4 acc[4][4];
#pragma unroll
  for (int i = 0; i < 4; i++)
#pragma unroll
    for (int j = 0; j < 4; j++) acc[i][j] = (floatx4){0.f, 0.f, 0.f, 0.f};

  mm_core64(A, Bt, Hdim, Hdim, Hdim, m0, n0, wv, lane, wm, wn, As, Bs, acc);

  const int r0 = wm * 64 + ((lane >> 4) << 2);
  const int c0 = wn * 64 + (lane & 15);
#pragma unroll
  for (int mt = 0; mt < 4; mt++) {
#pragma unroll
    for (int i = 0; i < 4; i++) {
      long r = m0 + r0 + mt * 16 + i;
      long bidx = r * (long)CHUNK + n0 + c0;
#pragma unroll
      for (int nt = 0; nt < 4; nt++) {
        long idx = bidx + nt * 16;
        float v = acc[mt][nt][i];
        float o;
        if (sub == 0)      o = __expf(fminf(v, 60.f));
        else if (sub == 1) o = v;
        else               o = 1.f / (1.f + __expf(-v));
        C[idx] = f2bf(o);
      }
    }
  }
}

// ---------------- launch ----------------
extern "C" void kernel_launch(void* const* d_in, const int* in_sizes, int n_in,
                              void* d_out, int out_size, void* d_ws, size_t ws_size,
                              hipStream_t stream) {
  (void)in_sizes; (void)n_in; (void)out_size; (void)ws_size;
  const float* x        = (const float*)d_in[0];
  const float* ln0_g    = (const float*)d_in[1];
  const float* ln0_b    = (const float*)d_in[2];
  const float* pre_g    = (const float*)d_in[3];
  const float* pre_b    = (const float*)d_in[4];
  const float* post_g   = (const float*)d_in[5];
  const float* post_b   = (const float*)d_in[6];
  const float* tm_decay = (const float*)d_in[7];
  const float* tm_first = (const float*)d_in[8];
  const float* tm_mix_k = (const float*)d_in[9];
  const float* tm_mix_v = (const float*)d_in[10];
  const float* tm_mix_r = (const float*)d_in[11];
  const float* tm_Wk    = (const float*)d_in[12];
  const float* tm_Wv    = (const float*)d_in[13];
  const float* tm_Wr    = (const float*)d_in[14];
  const float* tm_Wo    = (const float*)d_in[15];
  const float* cm_mix_k = (const float*)d_in[16];
  const float* cm_mix_r = (const float*)d_in[17];
  const float* cm_Wk    = (const float*)d_in[18];
  const float* cm_Wv    = (const float*)d_in[19];
  const float* cm_Wr    = (const float*)d_in[20];

  char* ws = (char*)d_ws;
  // static layout (bytes); peak 238,026,752 (227 MiB)
  bf16*  WkT  = (bf16*)(ws + 0);          // [HU,H]
  bf16*  WvT  = (bf16*)(ws + 8388608);    // [HU,H]
  bf16*  WrT  = (bf16*)(ws + 16777216);   // [HU,H]
  bf16*  WoT  = (bf16*)(ws + 25165824);   // [H,HU]
  bf16*  cWkT = (bf16*)(ws + 33554432);   // [HU,H]
  bf16*  cWvT = (bf16*)(ws + 41943040);   // [H,HU]
  bf16*  cWrT = (bf16*)(ws + 50331648);   // [H,H]
  float* xres = (float*)(ws + 52428800);  // [M,H] f32: x0 -> x1 (atomic accum)
  bf16*  xk   = (bf16*)(ws + 85983232);   // [M,H]
  bf16*  xv   = (bf16*)(ws + 102760448);
  bf16*  xr   = (bf16*)(ws + 119537664);
  bf16*  Kc   = (bf16*)(ws + 136314880);  // [M,CHUNK]
  bf16*  Vc   = (bf16*)(ws + 169869312);  // [M,CHUNK]
  bf16*  SRc  = (bf16*)(ws + 203423744);  // [M,CHUNK], P written in place
  float* stK  = (float*)(ws + 236978176); // [NSEG,B,CHUNK] f32 (512 KiB)
  float* stKV = (float*)(ws + 237502464); // [NSEG,B,CHUNK] f32 (512 KiB)
  // CM-phase aliases (regions dead by then):
  bf16*  xk2  = (bf16*)(ws + 136314880);  // over Kc
  bf16*  xr2  = (bf16*)(ws + 153092096);  // over Kc (2nd half)
  bf16*  hbuf = (bf16*)(ws + 169869312);  // [M,HU] over Vc+SRc (67,108,864 B)
  float* hv   = (float*)(ws + 85983232);  // [M,H] f32 over xk+xv

  dim3 blk(256);
  wconv_all<<<6400, blk, 0, stream>>>(tm_Wk, tm_Wv, tm_Wr, tm_Wo, cm_Wk, cm_Wv, cm_Wr,
                                      WkT, WvT, WrT, WoT, cWkT, cWvT, cWrT);

  ln_mix_tm<<<Mrows, blk, 0, stream>>>(x, ln0_g, ln0_b, pre_g, pre_b,
                                       tm_mix_k, tm_mix_v, tm_mix_r, xres, xk, xv, xr);

  const int scan_grid = NSEG * Bdim * (CHUNK / 64);   // 2048 blocks
  const int GM = Mrows / 128;                          // 64
  const int GNp = CHUNK / 128;                         // 16
  for (int ch = 0; ch < NCH; ch++) {
    const long woff = (long)ch * CHUNK;
    proj3<<<3 * GM * GNp, blk, 0, stream>>>(
        xk, xv, xr, WkT + woff * Hdim, WvT + woff * Hdim, WrT + woff * Hdim,
        Kc, Vc, SRc, GM, GNp);

    wkv_part<<<scan_grid, dim3(64), 0, stream>>>(
        Kc, Vc, stK, stKV, tm_decay + woff);
    wkv_emit<<<scan_grid, dim3(64), 0, stream>>>(
        Kc, Vc, SRc, SRc, stK, stKV, tm_decay + woff, tm_first + woff);

    // xres += P_ch @ Wo[ch*CHUNK:,:]  -- split-K x2 (K=1024/slice), atomic f32 accum
    gemm_bt<E_ATOMIC, 2><<<2 * GM * (Hdim/128), blk, 0, stream>>>(
        SRc, WoT + woff, xres, nullptr, nullptr, CHUNK, HUdim, Hdim, 1024, GM, Hdim/128);
  }

  ln_mix_cm<<<Mrows, blk, 0, stream>>>(xres, post_g, post_b, cm_mix_k, cm_mix_r, xk2, xr2);

  hipMemsetAsync(hv, 0, (size_t)Mrows * Hdim * 4, stream);

  // hbuf = silu(xk2 @ cWk) over full HU in one launch (2048 blocks)
  gemm_bt<E_SILU, 1><<<GM * (HUdim/128), blk, 0, stream>>>(
      xk2, cWkT, hbuf, nullptr, nullptr, Hdim, Hdim, HUdim, Hdim, GM, HUdim/128);

  // hv = hbuf @ cWv (K=4096) -- split-K x4 (K=1024/slice), atomic f32 accum
  gemm_bt<E_ATOMIC, 4><<<4 * GM * (Hdim/128), blk, 0, stream>>>(
      hbuf, cWvT, hv, nullptr, nullptr, HUdim, HUdim, Hdim, 1024, GM, Hdim/128);

  gemm_bt<E_SIGADD2, 1><<<GM * (Hdim/128), blk, 0, stream>>>(
      xr2, cWrT, (float*)d_out, xres, hv, Hdim, Hdim, Hdim, 1024, GM, Hdim/128);
}

// Round 7
// 994.161 us; speedup vs baseline: 1.1191x; 1.1191x over previous
//
#include <hip/hip_runtime.h>

#define Hdim  1024
#define Tdim  2048
#define Bdim  4
#define HUdim 4096
#define Mrows (Bdim*Tdim)   // 8192
#define CHUNK 2048          // HU processed in HUdim/CHUNK slices
#define NCH   (HUdim/CHUNK) // 2
#define NSEG  16            // T-segments for parallel scan
#define SEGL  (Tdim/NSEG)   // 128
#define SCHUNK 16

typedef __bf16 bf16;
typedef __bf16 bf16x8 __attribute__((ext_vector_type(8)));
typedef float  floatx4 __attribute__((ext_vector_type(4)));

__device__ __forceinline__ bf16 f2bf(float x) { return (bf16)x; }

// ---------------- fused weight transpose + f32->bf16 convert (all 7 weights) ----------------
__global__ __launch_bounds__(256) void wconv_all(
    const float* __restrict__ s0, const float* __restrict__ s1, const float* __restrict__ s2,
    const float* __restrict__ s3, const float* __restrict__ s4, const float* __restrict__ s5,
    const float* __restrict__ s6,
    bf16* d0, bf16* d1, bf16* d2, bf16* d3, bf16* d4, bf16* d5, bf16* d6) {
  __shared__ float tile[64][65];
  int bid = blockIdx.x;
  const float* src; bf16* dst; int K, N, local;
  if (bid < 1024)      { src = s0; dst = d0; K = Hdim;  N = HUdim; local = bid; }
  else if (bid < 2048) { src = s1; dst = d1; K = Hdim;  N = HUdim; local = bid - 1024; }
  else if (bid < 3072) { src = s2; dst = d2; K = Hdim;  N = HUdim; local = bid - 2048; }
  else if (bid < 4096) { src = s3; dst = d3; K = HUdim; N = Hdim;  local = bid - 3072; }
  else if (bid < 5120) { src = s4; dst = d4; K = Hdim;  N = HUdim; local = bid - 4096; }
  else if (bid < 6144) { src = s5; dst = d5; K = HUdim; N = Hdim;  local = bid - 5120; }
  else                 { src = s6; dst = d6; K = Hdim;  N = Hdim;  local = bid - 6144; }
  const int nt = N >> 6;
  const int n0 = (local % nt) * 64, k0 = (local / nt) * 64;
  const int tr = threadIdx.x >> 6;   // 0..3
  const int tc = threadIdx.x & 63;
#pragma unroll
  for (int j = 0; j < 16; j++) {
    int r = j * 4 + tr;
    tile[r][tc] = src[(size_t)(k0 + r) * N + n0 + tc];
  }
  __syncthreads();
#pragma unroll
  for (int j = 0; j < 16; j++) {
    int r = j * 4 + tr;
    dst[(size_t)(n0 + r) * K + k0 + tc] = f2bf(tile[tc][r]);
  }
}

// ---------------- block reduction helper (256 threads, 4 values) ----------------
__device__ __forceinline__ void block_reduce4(float v[4], float* sm) {
#pragma unroll
  for (int off = 32; off > 0; off >>= 1) {
#pragma unroll
    for (int i = 0; i < 4; i++) v[i] += __shfl_down(v[i], off, 64);
  }
  const int w = threadIdx.x >> 6;
  if ((threadIdx.x & 63) == 0) {
#pragma unroll
    for (int i = 0; i < 4; i++) sm[w * 4 + i] = v[i];
  }
  __syncthreads();
#pragma unroll
  for (int i = 0; i < 4; i++) v[i] = sm[i] + sm[4 + i] + sm[8 + i] + sm[12 + i];
  __syncthreads();
}

// ---------------- ln0 + pre-LN + shift + TM mixes ----------------
__global__ __launch_bounds__(256) void ln_mix_tm(
    const float* __restrict__ x,
    const float* __restrict__ g0, const float* __restrict__ b0,
    const float* __restrict__ g1, const float* __restrict__ b1,
    const float* __restrict__ mk, const float* __restrict__ mv, const float* __restrict__ mr,
    float* __restrict__ x0, bf16* __restrict__ xk, bf16* __restrict__ xv, bf16* __restrict__ xr) {
  __shared__ float sm[16];
  const int bid = blockIdx.x;
  const int t = bid & (Tdim - 1);
  const int tid = threadIdx.x;
  const bool havep = (t > 0);
  const float hp = havep ? 1.f : 0.f;
  const float* rowc = x + (size_t)bid * Hdim;
  const float* rowp = havep ? (rowc - Hdim) : rowc;  // always in-bounds

  float c[4], p[4];
#pragma unroll
  for (int j = 0; j < 4; j++) c[j] = rowc[tid * 4 + j];
#pragma unroll
  for (int j = 0; j < 4; j++) p[j] = rowp[tid * 4 + j] * hp;

  float red[4] = {0.f, 0.f, 0.f, 0.f};
#pragma unroll
  for (int j = 0; j < 4; j++) { red[0] += c[j]; red[1] += c[j]*c[j]; red[2] += p[j]; red[3] += p[j]*p[j]; }
  block_reduce4(red, sm);
  const float inv = 1.f / Hdim;
  float mc = red[0]*inv, vc = red[1]*inv - mc*mc;
  float mp = red[2]*inv, vp = red[3]*inv - mp*mp;
  float sc = rsqrtf(vc + 1e-5f), sp = rsqrtf(vp + 1e-5f);

  float yc[4], yp[4];
#pragma unroll
  for (int j = 0; j < 4; j++) {
    int i = tid * 4 + j;
    yc[j] = (c[j] - mc) * sc * g0[i] + b0[i];
    yp[j] = ((p[j] - mp) * sp * g0[i] + b0[i]) * hp;
    x0[(size_t)bid * Hdim + i] = yc[j];
  }

  float r2[4] = {0.f, 0.f, 0.f, 0.f};
#pragma unroll
  for (int j = 0; j < 4; j++) { r2[0] += yc[j]; r2[1] += yc[j]*yc[j]; r2[2] += yp[j]; r2[3] += yp[j]*yp[j]; }
  block_reduce4(r2, sm);
  float mc2 = r2[0]*inv, vc2 = r2[1]*inv - mc2*mc2;
  float mp2 = r2[2]*inv, vp2 = r2[3]*inv - mp2*mp2;
  float sc2 = rsqrtf(vc2 + 1e-5f), sp2 = rsqrtf(vp2 + 1e-5f);

#pragma unroll
  for (int j = 0; j < 4; j++) {
    int i = tid * 4 + j;
    float xnc = (yc[j] - mc2) * sc2 * g1[i] + b1[i];
    float xnp = ((yp[j] - mp2) * sp2 * g1[i] + b1[i]) * hp;
    size_t o = (size_t)bid * Hdim + i;
    float a;
    a = mk[i]; xk[o] = f2bf(xnc * a + xnp * (1.f - a));
    a = mv[i]; xv[o] = f2bf(xnc * a + xnp * (1.f - a));
    a = mr[i]; xr[o] = f2bf(xnc * a + xnp * (1.f - a));
  }
}

// ---------------- post-LN + shift + CM mixes ----------------
__global__ __launch_bounds__(256) void ln_mix_cm(
    const float* __restrict__ xin,
    const float* __restrict__ g, const float* __restrict__ bb,
    const float* __restrict__ mk, const float* __restrict__ mr,
    bf16* __restrict__ xk, bf16* __restrict__ xr) {
  __shared__ float sm[16];
  const int bid = blockIdx.x;
  const int t = bid & (Tdim - 1);
  const int tid = threadIdx.x;
  const bool havep = (t > 0);
  const float hp = havep ? 1.f : 0.f;
  const float* rowc = xin + (size_t)bid * Hdim;
  const float* rowp = havep ? (rowc - Hdim) : rowc;

  float c[4], p[4];
#pragma unroll
  for (int j = 0; j < 4; j++) c[j] = rowc[tid * 4 + j];
#pragma unroll
  for (int j = 0; j < 4; j++) p[j] = rowp[tid * 4 + j] * hp;

  float red[4] = {0.f, 0.f, 0.f, 0.f};
#pragma unroll
  for (int j = 0; j < 4; j++) { red[0] += c[j]; red[1] += c[j]*c[j]; red[2] += p[j]; red[3] += p[j]*p[j]; }
  block_reduce4(red, sm);
  const float inv = 1.f / Hdim;
  float mc = red[0]*inv, vc = red[1]*inv - mc*mc;
  float mp = red[2]*inv, vp = red[3]*inv - mp*mp;
  float sc = rsqrtf(vc + 1e-5f), sp = rsqrtf(vp + 1e-5f);

#pragma unroll
  for (int j = 0; j < 4; j++) {
    int i = tid * 4 + j;
    float xnc = (c[j] - mc) * sc * g[i] + bb[i];
    float xnp = ((p[j] - mp) * sp * g[i] + bb[i]) * hp;
    size_t o = (size_t)bid * Hdim + i;
    float a;
    a = mk[i]; xk[o] = f2bf(xnc * a + xnp * (1.f - a));
    a = mr[i]; xr[o] = f2bf(xnc * a + xnp * (1.f - a));
  }
}

// ---------------- WKV parallel scan: pass A (per-segment end states) ----------------
__global__ __launch_bounds__(64) void wkv_part(
    const bf16* __restrict__ Kb, const bf16* __restrict__ Vb,
    float* __restrict__ stK, float* __restrict__ stKV,
    const float* __restrict__ tdec) {
  const int seg = blockIdx.x & (NSEG - 1);
  const int rest = blockIdx.x >> 4;       // b*32 + g
  const int b = rest >> 5, g = rest & 31;
  const int c = (g << 6) + threadIdx.x;
  const float decay = __expf(-__expf(tdec[c]));
  size_t base = ((size_t)b * Tdim + (size_t)seg * SEGL) * CHUNK + c;
  float sk = 0.f, skv = 0.f;
  for (int t0 = 0; t0 < SEGL; t0 += SCHUNK) {
    float kk[SCHUNK], vv[SCHUNK];
#pragma unroll
    for (int j = 0; j < SCHUNK; j++) {
      size_t idx = base + (size_t)(t0 + j) * CHUNK;
      kk[j] = (float)Kb[idx];
      vv[j] = (float)Vb[idx];
    }
#pragma unroll
    for (int j = 0; j < SCHUNK; j++) {
      float kvt = kk[j] * vv[j];
      sk  = fmaf(decay, sk, kk[j]);
      skv = fmaf(decay, skv, kvt);
    }
  }
  size_t so = ((size_t)seg * Bdim + b) * CHUNK + c;
  stK[so]  = sk;
  stKV[so] = skv;
}

// ---------------- WKV parallel scan: pass B (fold carry, emit P) ----------------
__global__ __launch_bounds__(64) void wkv_emit(
    const bf16* __restrict__ Kb, const bf16* __restrict__ Vb,
    const bf16* SRb, bf16* Pb,   // SRb/Pb alias: per-element read-before-write
    const float* __restrict__ stK, const float* __restrict__ stKV,
    const float* __restrict__ tdec, const float* __restrict__ tfst) {
  const int seg = blockIdx.x & (NSEG - 1);
  const int rest = blockIdx.x >> 4;
  const int b = rest >> 5, g = rest & 31;
  const int c = (g << 6) + threadIdx.x;
  const float ed = __expf(tdec[c]);
  const float decay = __expf(-ed);
  const float dfac  = __expf(-ed * (float)SEGL);   // decay^SEGL, exact closed form
  const float first = __expf(tfst[c]);

  float sk = 0.f, skv = 0.f;
  for (int j = 0; j < seg; j++) {
    size_t so = ((size_t)j * Bdim + b) * CHUNK + c;
    sk  = fmaf(dfac, sk, stK[so]);
    skv = fmaf(dfac, skv, stKV[so]);
  }

  size_t base = ((size_t)b * Tdim + (size_t)seg * SEGL) * CHUNK + c;
  for (int t0 = 0; t0 < SEGL; t0 += SCHUNK) {
    float kk[SCHUNK], vv[SCHUNK], rr[SCHUNK];
#pragma unroll
    for (int j = 0; j < SCHUNK; j++) {
      size_t idx = base + (size_t)(t0 + j) * CHUNK;
      kk[j] = (float)Kb[idx];
      vv[j] = (float)Vb[idx];
      rr[j] = (float)SRb[idx];
    }
#pragma unroll
    for (int j = 0; j < SCHUNK; j++) {
      size_t idx = base + (size_t)(t0 + j) * CHUNK;
      float kvt = kk[j] * vv[j];
      float wk  = fmaf(first, kk[j], sk) + 1e-8f;
      float wkv = fmaf(first, kvt, skv);
      Pb[idx] = f2bf(rr[j] * wkv * __builtin_amdgcn_rcpf(wk));
      sk  = fmaf(decay, sk, kk[j]);
      skv = fmaf(decay, skv, kvt);
    }
  }
}

// ---------------- MFMA GEMM core (BK=64, bank-conflict phase swizzle) ----------------
// LDS tile 128x32 per sub-tile; logical col-group cg of row r stored at physical
// group (cg + (r>>1)) & 3. Staging permutes the GLOBAL source column per lane
// (same 64B segments, coalescing unchanged); readers add the matching phase.
// Result: fragment ds_read_b128 goes 8-way -> 2-way bank aliasing (free, m136).
__device__ __forceinline__ void gld_lds(const bf16* g, bf16* l) {
  __builtin_amdgcn_global_load_lds(
      (const __attribute__((address_space(1))) void*)(g),
      (__attribute__((address_space(3))) void*)(l),
      16, 0, 0);
}

// XCD-aware swizzle: xcd=s%8 owns m-band [xcd*gm/8,...); n in groups of 2, m fastest.
__device__ __forceinline__ void swz(int s, int gm, int& m_t, int& n_t) {
  const int mpx  = gm >> 3;        // gm % 8 == 0 at all call sites
  const int xcd  = s & 7;
  const int ss   = s >> 3;
  const int pass = mpx << 1;
  const int ng   = ss / pass;
  const int rem  = ss - ng * pass;
  m_t = xcd * mpx + (rem >> 1);
  n_t = (ng << 1) + (rem & 1);
}

__device__ __forceinline__ void mm_core64(
    const bf16* A, const bf16* Bt, int lda, int ldb, int K,
    long m0, long n0, int wv, int lane, int wm, int wn,
    bf16* As, bf16* Bs, floatx4 acc[4][4]) {
  const int srow = wv * 32 + (lane >> 2);
  // staging column: physical slot = lane&3; fetch logical group (slot - phase) & 3
  // phase = (srow>>1)&3 == (lane>>3)&3  (wv*32 contributes 0 mod 4)
  const int scol = (((lane & 3) - ((lane >> 3) & 3)) & 3) * 8;
  const bf16* gA = A + (m0 + srow) * (long)lda + scol;
  const bf16* gB = Bt + (n0 + srow) * (long)ldb + scol;
  const long skipA = 16L * lda;   // +16 rows: phase shift 8 == 0 mod 4 -> scol valid
  const long skipB = 16L * ldb;
  bf16* lA = As + wv * 1024;
  bf16* lB = Bs + wv * 1024;
  // fragment read: logical cg = lane>>4, row phase = (lane>>1)&3 (wm*64, mt*16 are 0 mod 4)
  const int pg = ((lane >> 4) + ((lane >> 1) & 3)) & 3;
  const bf16* fa = As + ((wm * 64) + (lane & 15)) * 32 + pg * 8;
  const bf16* fb = Bs + ((wn * 64) + (lane & 15)) * 32 + pg * 8;

  const int ksteps = K >> 6;
  for (int kt = 0; kt < ksteps; ++kt) {
    __syncthreads();
    gld_lds(gA, lA);             gld_lds(gA + skipA, lA + 512);
    gld_lds(gA + 32, lA + 4096); gld_lds(gA + 32 + skipA, lA + 4096 + 512);
    gld_lds(gB, lB);             gld_lds(gB + skipB, lB + 512);
    gld_lds(gB + 32, lB + 4096); gld_lds(gB + 32 + skipB, lB + 4096 + 512);
    gA += 64; gB += 64;
    __syncthreads();
#pragma unroll
    for (int s = 0; s < 2; s++) {
      bf16x8 af[4], bfr[4];
#pragma unroll
      for (int i = 0; i < 4; i++) {
        af[i]  = *(const bf16x8*)(fa + s * 4096 + i * 512);
        bfr[i] = *(const bf16x8*)(fb + s * 4096 + i * 512);
      }
#pragma unroll
      for (int mt = 0; mt < 4; mt++)
#pragma unroll
        for (int nt = 0; nt < 4; nt++)
          acc[mt][nt] = __builtin_amdgcn_mfma_f32_16x16x32_bf16(af[mt], bfr[nt], acc[mt][nt], 0, 0, 0);
    }
  }
}

enum { E_EXP = 0, E_BF16 = 1, E_SIG = 2, E_ADD1 = 3, E_SILU = 4, E_F32 = 5, E_SIGADD2 = 6 };

template <int EPI>
__global__ __launch_bounds__(256) void gemm_bt(
    const bf16* __restrict__ A, const bf16* __restrict__ Bt,
    void* Cout, const void* aux1, const void* aux2,
    int lda, int ldb, int ldc, int K, int gm, int gn) {
  __shared__ __align__(16) bf16 As[2 * 128 * 32];
  __shared__ __align__(16) bf16 Bs[2 * 128 * 32];
  const int tid = threadIdx.x;
  const int lane = tid & 63;
  const int wv = tid >> 6;
  const int wm = wv >> 1, wn = wv & 1;
  int m_t, n_t;
  swz(blockIdx.x, gm, m_t, n_t);
  const long m0 = (long)m_t * 128;
  const long n0 = (long)n_t * 128;

  floatx4 acc[4][4];
#pragma unroll
  for (int i = 0; i < 4; i++)
#pragma unroll
    for (int j = 0; j < 4; j++) acc[i][j] = (floatx4){0.f, 0.f, 0.f, 0.f};

  mm_core64(A, Bt, lda, ldb, K, m0, n0, wv, lane, wm, wn, As, Bs, acc);

  const int r0 = wm * 64 + ((lane >> 4) << 2);
  const int c0 = wn * 64 + (lane & 15);
#pragma unroll
  for (int mt = 0; mt < 4; mt++) {
#pragma unroll
    for (int i = 0; i < 4; i++) {
      long r = m0 + r0 + mt * 16 + i;
      long bidx = r * (long)ldc + n0 + c0;
#pragma unroll
      for (int nt = 0; nt < 4; nt++) {
        long idx = bidx + nt * 16;
        float v = acc[mt][nt][i];
        if constexpr (EPI == E_EXP) {
          ((bf16*)Cout)[idx] = f2bf(__expf(fminf(v, 60.f)));
        } else if constexpr (EPI == E_BF16) {
          ((bf16*)Cout)[idx] = f2bf(v);
        } else if constexpr (EPI == E_SIG) {
          ((bf16*)Cout)[idx] = f2bf(1.f / (1.f + __expf(-v)));
        } else if constexpr (EPI == E_ADD1) {
          float prev = ((const float*)aux1)[idx];   // may alias Cout (same idx)
          ((float*)Cout)[idx] = v + prev;
        } else if constexpr (EPI == E_SILU) {
          ((bf16*)Cout)[idx] = f2bf(v / (1.f + __expf(-v)));
        } else if constexpr (EPI == E_F32) {
          ((float*)Cout)[idx] = v;
        } else {  // E_SIGADD2
          float a1 = ((const float*)aux1)[idx];
          float a2 = ((const float*)aux2)[idx];
          ((float*)Cout)[idx] = a1 + 1.f / (1.f + __expf(-v)) + a2;
        }
      }
    }
  }
}

// ---------------- fused K/V/R projection: 3 GEMMs in one launch ----------------
__global__ __launch_bounds__(256) void proj3(
    const bf16* __restrict__ xk, const bf16* __restrict__ xv, const bf16* __restrict__ xr,
    const bf16* __restrict__ Wk, const bf16* __restrict__ Wv, const bf16* __restrict__ Wr,
    bf16* Kc, bf16* Vc, bf16* SRc, int gm, int gn) {
  __shared__ __align__(16) bf16 As[2 * 128 * 32];
  __shared__ __align__(16) bf16 Bs[2 * 128 * 32];
  const int per = gm * gn;
  const int sub = blockIdx.x / per;          // 0:K 1:V 2:R
  const int s   = blockIdx.x - sub * per;
  const int tid = threadIdx.x;
  const int lane = tid & 63;
  const int wv = tid >> 6;
  const int wm = wv >> 1, wn = wv & 1;
  int m_t, n_t;
  swz(s, gm, m_t, n_t);
  const long m0 = (long)m_t * 128;
  const long n0 = (long)n_t * 128;

  const bf16* A  = (sub == 0) ? xk : (sub == 1) ? xv : xr;
  const bf16* Bt = (sub == 0) ? Wk : (sub == 1) ? Wv : Wr;
  bf16*       C  = (sub == 0) ? Kc : (sub == 1) ? Vc : SRc;

  floatx4 acc[4][4];
#pragma unroll
  for (int i = 0; i < 4; i++)
#pragma unroll
    for (int j = 0; j < 4; j++) acc[i][j] = (floatx4){0.f, 0.f, 0.f, 0.f};

  mm_core64(A, Bt, Hdim, Hdim, Hdim, m0, n0, wv, lane, wm, wn, As, Bs, acc);

  const int r0 = wm * 64 + ((lane >> 4) << 2);
  const int c0 = wn * 64 + (lane & 15);
#pragma unroll
  for (int mt = 0; mt < 4; mt++) {
#pragma unroll
    for (int i = 0; i < 4; i++) {
      long r = m0 + r0 + mt * 16 + i;
      long bidx = r * (long)CHUNK + n0 + c0;
#pragma unroll
      for (int nt = 0; nt < 4; nt++) {
        long idx = bidx + nt * 16;
        float v = acc[mt][nt][i];
        float o;
        if (sub == 0)      o = __expf(fminf(v, 60.f));
        else if (sub == 1) o = v;
        else               o = 1.f / (1.f + __expf(-v));
        C[idx] = f2bf(o);
      }
    }
  }
}

// ---------------- launch ----------------
extern "C" void kernel_launch(void* const* d_in, const int* in_sizes, int n_in,
                              void* d_out, int out_size, void* d_ws, size_t ws_size,
                              hipStream_t stream) {
  (void)in_sizes; (void)n_in; (void)out_size; (void)ws_size;
  const float* x        = (const float*)d_in[0];
  const float* ln0_g    = (const float*)d_in[1];
  const float* ln0_b    = (const float*)d_in[2];
  const float* pre_g    = (const float*)d_in[3];
  const float* pre_b    = (const float*)d_in[4];
  const float* post_g   = (const float*)d_in[5];
  const float* post_b   = (const float*)d_in[6];
  const float* tm_decay = (const float*)d_in[7];
  const float* tm_first = (const float*)d_in[8];
  const float* tm_mix_k = (const float*)d_in[9];
  const float* tm_mix_v = (const float*)d_in[10];
  const float* tm_mix_r = (const float*)d_in[11];
  const float* tm_Wk    = (const float*)d_in[12];
  const float* tm_Wv    = (const float*)d_in[13];
  const float* tm_Wr    = (const float*)d_in[14];
  const float* tm_Wo    = (const float*)d_in[15];
  const float* cm_mix_k = (const float*)d_in[16];
  const float* cm_mix_r = (const float*)d_in[17];
  const float* cm_Wk    = (const float*)d_in[18];
  const float* cm_Wv    = (const float*)d_in[19];
  const float* cm_Wr    = (const float*)d_in[20];

  char* ws = (char*)d_ws;
  // static layout (bytes); peak 238,026,752 (227 MiB)
  bf16*  WkT  = (bf16*)(ws + 0);          // [HU,H]
  bf16*  WvT  = (bf16*)(ws + 8388608);    // [HU,H]
  bf16*  WrT  = (bf16*)(ws + 16777216);   // [HU,H]
  bf16*  WoT  = (bf16*)(ws + 25165824);   // [H,HU]
  bf16*  cWkT = (bf16*)(ws + 33554432);   // [HU,H]
  bf16*  cWvT = (bf16*)(ws + 41943040);   // [H,HU]
  bf16*  cWrT = (bf16*)(ws + 50331648);   // [H,H]
  float* xres = (float*)(ws + 52428800);  // [M,H] f32: x0 -> x1 (in-place accum)
  bf16*  xk   = (bf16*)(ws + 85983232);   // [M,H]
  bf16*  xv   = (bf16*)(ws + 102760448);
  bf16*  xr   = (bf16*)(ws + 119537664);
  bf16*  Kc   = (bf16*)(ws + 136314880);  // [M,CHUNK]
  bf16*  Vc   = (bf16*)(ws + 169869312);  // [M,CHUNK]
  bf16*  SRc  = (bf16*)(ws + 203423744);  // [M,CHUNK], P written in place
  float* stK  = (float*)(ws + 236978176); // [NSEG,B,CHUNK] f32 (512 KiB)
  float* stKV = (float*)(ws + 237502464); // [NSEG,B,CHUNK] f32 (512 KiB)
  // CM-phase aliases (regions dead by then):
  bf16*  xk2  = (bf16*)(ws + 136314880);  // over Kc
  bf16*  xr2  = (bf16*)(ws + 153092096);  // over Kc (2nd half)
  bf16*  hbuf = (bf16*)(ws + 169869312);  // [M,HU] over Vc+SRc (67,108,864 B)
  float* hv   = (float*)(ws + 85983232);  // [M,H] f32 over xk+xv

  dim3 blk(256);
  wconv_all<<<6400, blk, 0, stream>>>(tm_Wk, tm_Wv, tm_Wr, tm_Wo, cm_Wk, cm_Wv, cm_Wr,
                                      WkT, WvT, WrT, WoT, cWkT, cWvT, cWrT);

  ln_mix_tm<<<Mrows, blk, 0, stream>>>(x, ln0_g, ln0_b, pre_g, pre_b,
                                       tm_mix_k, tm_mix_v, tm_mix_r, xres, xk, xv, xr);

  const int scan_grid = NSEG * Bdim * (CHUNK / 64);   // 2048 blocks
  const int GM = Mrows / 128;                          // 64
  const int GNp = CHUNK / 128;                         // 16
  for (int ch = 0; ch < NCH; ch++) {
    const long woff = (long)ch * CHUNK;
    proj3<<<3 * GM * GNp, blk, 0, stream>>>(
        xk, xv, xr, WkT + woff * Hdim, WvT + woff * Hdim, WrT + woff * Hdim,
        Kc, Vc, SRc, GM, GNp);

    wkv_part<<<scan_grid, dim3(64), 0, stream>>>(
        Kc, Vc, stK, stKV, tm_decay + woff);
    wkv_emit<<<scan_grid, dim3(64), 0, stream>>>(
        Kc, Vc, SRc, SRc, stK, stKV, tm_decay + woff, tm_first + woff);

    // xres += P_ch @ Wo[ch*CHUNK:,:]
    gemm_bt<E_ADD1><<<GM * (Hdim/128), blk, 0, stream>>>(
        SRc, WoT + woff, xres, xres, nullptr, CHUNK, HUdim, Hdim, CHUNK, GM, Hdim/128);
  }

  ln_mix_cm<<<Mrows, blk, 0, stream>>>(xres, post_g, post_b, cm_mix_k, cm_mix_r, xk2, xr2);

  // hbuf = silu(xk2 @ cWk) over full HU in one launch (2048 blocks)
  gemm_bt<E_SILU><<<GM * (HUdim/128), blk, 0, stream>>>(
      xk2, cWkT, hbuf, nullptr, nullptr, Hdim, Hdim, HUdim, Hdim, GM, HUdim/128);

  // hv = hbuf @ cWv (K=4096) as two chained K=2048 halves
  gemm_bt<E_F32><<<GM * (Hdim/128), blk, 0, stream>>>(
      hbuf, cWvT, hv, nullptr, nullptr, HUdim, HUdim, Hdim, CHUNK, GM, Hdim/128);
  gemm_bt<E_ADD1><<<GM * (Hdim/128), blk, 0, stream>>>(
      hbuf + CHUNK, cWvT + CHUNK, hv, hv, nullptr, HUdim, HUdim, Hdim, CHUNK, GM, Hdim/128);

  gemm_bt<E_SIGADD2><<<GM * (Hdim/128), blk, 0, stream>>>(
      xr2, cWrT, (float*)d_out, xres, hv, Hdim, Hdim, Hdim, Hdim, GM, Hdim/128);
}

// Round 8
// 987.882 us; speedup vs baseline: 1.1262x; 1.0064x over previous
//
#include <hip/hip_runtime.h>

#define Hdim  1024
#define Tdim  2048
#define Bdim  4
#define HUdim 4096
#define Mrows (Bdim*Tdim)   // 8192
#define CHUNK 2048          // HU processed in HUdim/CHUNK slices
#define NCH   (HUdim/CHUNK) // 2
#define NSEG  16            // T-segments for parallel scan
#define SEGL  (Tdim/NSEG)   // 128
#define SCHUNK 16

typedef __bf16 bf16;
typedef __bf16 bf16x2 __attribute__((ext_vector_type(2)));
typedef __bf16 bf16x8 __attribute__((ext_vector_type(8)));
typedef float  floatx4 __attribute__((ext_vector_type(4)));

__device__ __forceinline__ bf16 f2bf(float x) { return (bf16)x; }

// ---------------- fused weight transpose + f32->bf16 convert (all 7 weights) ----------------
__global__ __launch_bounds__(256) void wconv_all(
    const float* __restrict__ s0, const float* __restrict__ s1, const float* __restrict__ s2,
    const float* __restrict__ s3, const float* __restrict__ s4, const float* __restrict__ s5,
    const float* __restrict__ s6,
    bf16* d0, bf16* d1, bf16* d2, bf16* d3, bf16* d4, bf16* d5, bf16* d6) {
  __shared__ float tile[64][65];
  int bid = blockIdx.x;
  const float* src; bf16* dst; int K, N, local;
  if (bid < 1024)      { src = s0; dst = d0; K = Hdim;  N = HUdim; local = bid; }
  else if (bid < 2048) { src = s1; dst = d1; K = Hdim;  N = HUdim; local = bid - 1024; }
  else if (bid < 3072) { src = s2; dst = d2; K = Hdim;  N = HUdim; local = bid - 2048; }
  else if (bid < 4096) { src = s3; dst = d3; K = HUdim; N = Hdim;  local = bid - 3072; }
  else if (bid < 5120) { src = s4; dst = d4; K = Hdim;  N = HUdim; local = bid - 4096; }
  else if (bid < 6144) { src = s5; dst = d5; K = HUdim; N = Hdim;  local = bid - 5120; }
  else                 { src = s6; dst = d6; K = Hdim;  N = Hdim;  local = bid - 6144; }
  const int nt = N >> 6;
  const int n0 = (local % nt) * 64, k0 = (local / nt) * 64;
  const int tr = threadIdx.x >> 6;   // 0..3
  const int tc = threadIdx.x & 63;
#pragma unroll
  for (int j = 0; j < 16; j++) {
    int r = j * 4 + tr;
    tile[r][tc] = src[(size_t)(k0 + r) * N + n0 + tc];
  }
  __syncthreads();
#pragma unroll
  for (int j = 0; j < 16; j++) {
    int r = j * 4 + tr;
    dst[(size_t)(n0 + r) * K + k0 + tc] = f2bf(tile[tc][r]);
  }
}

// ---------------- block reduction helper (256 threads, 4 values) ----------------
__device__ __forceinline__ void block_reduce4(float v[4], float* sm) {
#pragma unroll
  for (int off = 32; off > 0; off >>= 1) {
#pragma unroll
    for (int i = 0; i < 4; i++) v[i] += __shfl_down(v[i], off, 64);
  }
  const int w = threadIdx.x >> 6;
  if ((threadIdx.x & 63) == 0) {
#pragma unroll
    for (int i = 0; i < 4; i++) sm[w * 4 + i] = v[i];
  }
  __syncthreads();
#pragma unroll
  for (int i = 0; i < 4; i++) v[i] = sm[i] + sm[4 + i] + sm[8 + i] + sm[12 + i];
  __syncthreads();
}

// ---------------- ln0 + pre-LN + shift + TM mixes ----------------
__global__ __launch_bounds__(256) void ln_mix_tm(
    const float* __restrict__ x,
    const float* __restrict__ g0, const float* __restrict__ b0,
    const float* __restrict__ g1, const float* __restrict__ b1,
    const float* __restrict__ mk, const float* __restrict__ mv, const float* __restrict__ mr,
    float* __restrict__ x0, bf16* __restrict__ xk, bf16* __restrict__ xv, bf16* __restrict__ xr) {
  __shared__ float sm[16];
  const int bid = blockIdx.x;
  const int t = bid & (Tdim - 1);
  const int tid = threadIdx.x;
  const bool havep = (t > 0);
  const float hp = havep ? 1.f : 0.f;
  const float* rowc = x + (size_t)bid * Hdim;
  const float* rowp = havep ? (rowc - Hdim) : rowc;  // always in-bounds

  float c[4], p[4];
#pragma unroll
  for (int j = 0; j < 4; j++) c[j] = rowc[tid * 4 + j];
#pragma unroll
  for (int j = 0; j < 4; j++) p[j] = rowp[tid * 4 + j] * hp;

  float red[4] = {0.f, 0.f, 0.f, 0.f};
#pragma unroll
  for (int j = 0; j < 4; j++) { red[0] += c[j]; red[1] += c[j]*c[j]; red[2] += p[j]; red[3] += p[j]*p[j]; }
  block_reduce4(red, sm);
  const float inv = 1.f / Hdim;
  float mc = red[0]*inv, vc = red[1]*inv - mc*mc;
  float mp = red[2]*inv, vp = red[3]*inv - mp*mp;
  float sc = rsqrtf(vc + 1e-5f), sp = rsqrtf(vp + 1e-5f);

  float yc[4], yp[4];
#pragma unroll
  for (int j = 0; j < 4; j++) {
    int i = tid * 4 + j;
    yc[j] = (c[j] - mc) * sc * g0[i] + b0[i];
    yp[j] = ((p[j] - mp) * sp * g0[i] + b0[i]) * hp;
    x0[(size_t)bid * Hdim + i] = yc[j];
  }

  float r2[4] = {0.f, 0.f, 0.f, 0.f};
#pragma unroll
  for (int j = 0; j < 4; j++) { r2[0] += yc[j]; r2[1] += yc[j]*yc[j]; r2[2] += yp[j]; r2[3] += yp[j]*yp[j]; }
  block_reduce4(r2, sm);
  float mc2 = r2[0]*inv, vc2 = r2[1]*inv - mc2*mc2;
  float mp2 = r2[2]*inv, vp2 = r2[3]*inv - mp2*mp2;
  float sc2 = rsqrtf(vc2 + 1e-5f), sp2 = rsqrtf(vp2 + 1e-5f);

#pragma unroll
  for (int j = 0; j < 4; j++) {
    int i = tid * 4 + j;
    float xnc = (yc[j] - mc2) * sc2 * g1[i] + b1[i];
    float xnp = ((yp[j] - mp2) * sp2 * g1[i] + b1[i]) * hp;
    size_t o = (size_t)bid * Hdim + i;
    float a;
    a = mk[i]; xk[o] = f2bf(xnc * a + xnp * (1.f - a));
    a = mv[i]; xv[o] = f2bf(xnc * a + xnp * (1.f - a));
    a = mr[i]; xr[o] = f2bf(xnc * a + xnp * (1.f - a));
  }
}

// ---------------- post-LN + shift + CM mixes ----------------
__global__ __launch_bounds__(256) void ln_mix_cm(
    const float* __restrict__ xin,
    const float* __restrict__ g, const float* __restrict__ bb,
    const float* __restrict__ mk, const float* __restrict__ mr,
    bf16* __restrict__ xk, bf16* __restrict__ xr) {
  __shared__ float sm[16];
  const int bid = blockIdx.x;
  const int t = bid & (Tdim - 1);
  const int tid = threadIdx.x;
  const bool havep = (t > 0);
  const float hp = havep ? 1.f : 0.f;
  const float* rowc = xin + (size_t)bid * Hdim;
  const float* rowp = havep ? (rowc - Hdim) : rowc;

  float c[4], p[4];
#pragma unroll
  for (int j = 0; j < 4; j++) c[j] = rowc[tid * 4 + j];
#pragma unroll
  for (int j = 0; j < 4; j++) p[j] = rowp[tid * 4 + j] * hp;

  float red[4] = {0.f, 0.f, 0.f, 0.f};
#pragma unroll
  for (int j = 0; j < 4; j++) { red[0] += c[j]; red[1] += c[j]*c[j]; red[2] += p[j]; red[3] += p[j]*p[j]; }
  block_reduce4(red, sm);
  const float inv = 1.f / Hdim;
  float mc = red[0]*inv, vc = red[1]*inv - mc*mc;
  float mp = red[2]*inv, vp = red[3]*inv - mp*mp;
  float sc = rsqrtf(vc + 1e-5f), sp = rsqrtf(vp + 1e-5f);

#pragma unroll
  for (int j = 0; j < 4; j++) {
    int i = tid * 4 + j;
    float xnc = (c[j] - mc) * sc * g[i] + bb[i];
    float xnp = ((p[j] - mp) * sp * g[i] + bb[i]) * hp;
    size_t o = (size_t)bid * Hdim + i;
    float a;
    a = mk[i]; xk[o] = f2bf(xnc * a + xnp * (1.f - a));
    a = mr[i]; xr[o] = f2bf(xnc * a + xnp * (1.f - a));
  }
}

// ---------------- WKV parallel scan (2 channels/thread, bf16x2 loads) ----------------
// grid = NSEG * Bdim * (CHUNK/128), block 64. Thread owns channels c, c+1.
__global__ __launch_bounds__(64) void wkv_part(
    const bf16* __restrict__ Kb, const bf16* __restrict__ Vb,
    float* __restrict__ stK, float* __restrict__ stKV,
    const float* __restrict__ tdec) {
  const int seg = blockIdx.x & (NSEG - 1);
  const int rest = blockIdx.x >> 4;       // b*16 + g
  const int b = rest >> 4, g = rest & 15;
  const int c = (g << 7) + (threadIdx.x << 1);
  const float d0 = __expf(-__expf(tdec[c]));
  const float d1 = __expf(-__expf(tdec[c + 1]));
  size_t base = ((size_t)b * Tdim + (size_t)seg * SEGL) * CHUNK + c;
  float sk0 = 0.f, skv0 = 0.f, sk1 = 0.f, skv1 = 0.f;
  for (int t0 = 0; t0 < SEGL; t0 += SCHUNK) {
    bf16x2 kk[SCHUNK], vv[SCHUNK];
#pragma unroll
    for (int j = 0; j < SCHUNK; j++) {
      size_t idx = base + (size_t)(t0 + j) * CHUNK;
      kk[j] = *(const bf16x2*)(Kb + idx);
      vv[j] = *(const bf16x2*)(Vb + idx);
    }
#pragma unroll
    for (int j = 0; j < SCHUNK; j++) {
      float k0 = (float)kk[j][0], k1 = (float)kk[j][1];
      float v0 = (float)vv[j][0], v1 = (float)vv[j][1];
      sk0  = fmaf(d0, sk0, k0);   skv0 = fmaf(d0, skv0, k0 * v0);
      sk1  = fmaf(d1, sk1, k1);   skv1 = fmaf(d1, skv1, k1 * v1);
    }
  }
  size_t so = ((size_t)seg * Bdim + b) * CHUNK + c;
  stK[so]      = sk0;  stK[so + 1]  = sk1;
  stKV[so]     = skv0; stKV[so + 1] = skv1;
}

__global__ __launch_bounds__(64) void wkv_emit(
    const bf16* __restrict__ Kb, const bf16* __restrict__ Vb,
    const bf16* SRb, bf16* Pb,   // SRb/Pb alias: per-element read-before-write
    const float* __restrict__ stK, const float* __restrict__ stKV,
    const float* __restrict__ tdec, const float* __restrict__ tfst) {
  const int seg = blockIdx.x & (NSEG - 1);
  const int rest = blockIdx.x >> 4;
  const int b = rest >> 4, g = rest & 15;
  const int c = (g << 7) + (threadIdx.x << 1);
  const float ed0 = __expf(tdec[c]),     ed1 = __expf(tdec[c + 1]);
  const float d0  = __expf(-ed0),        d1  = __expf(-ed1);
  const float df0 = __expf(-ed0 * (float)SEGL);
  const float df1 = __expf(-ed1 * (float)SEGL);
  const float f0  = __expf(tfst[c]),     f1  = __expf(tfst[c + 1]);

  float sk0 = 0.f, skv0 = 0.f, sk1 = 0.f, skv1 = 0.f;
  for (int j = 0; j < seg; j++) {
    size_t so = ((size_t)j * Bdim + b) * CHUNK + c;
    sk0  = fmaf(df0, sk0,  stK[so]);      sk1  = fmaf(df1, sk1,  stK[so + 1]);
    skv0 = fmaf(df0, skv0, stKV[so]);     skv1 = fmaf(df1, skv1, stKV[so + 1]);
  }

  size_t base = ((size_t)b * Tdim + (size_t)seg * SEGL) * CHUNK + c;
  for (int t0 = 0; t0 < SEGL; t0 += SCHUNK) {
    bf16x2 kk[SCHUNK], vv[SCHUNK], rr[SCHUNK];
#pragma unroll
    for (int j = 0; j < SCHUNK; j++) {
      size_t idx = base + (size_t)(t0 + j) * CHUNK;
      kk[j] = *(const bf16x2*)(Kb + idx);
      vv[j] = *(const bf16x2*)(Vb + idx);
      rr[j] = *(const bf16x2*)(SRb + idx);
    }
#pragma unroll
    for (int j = 0; j < SCHUNK; j++) {
      size_t idx = base + (size_t)(t0 + j) * CHUNK;
      float k0 = (float)kk[j][0], k1 = (float)kk[j][1];
      float v0 = (float)vv[j][0], v1 = (float)vv[j][1];
      float kv0 = k0 * v0, kv1 = k1 * v1;
      float wk0  = fmaf(f0, k0, sk0) + 1e-8f;
      float wk1  = fmaf(f1, k1, sk1) + 1e-8f;
      float wkv0 = fmaf(f0, kv0, skv0);
      float wkv1 = fmaf(f1, kv1, skv1);
      bf16x2 out;
      out[0] = f2bf((float)rr[j][0] * wkv0 * __builtin_amdgcn_rcpf(wk0));
      out[1] = f2bf((float)rr[j][1] * wkv1 * __builtin_amdgcn_rcpf(wk1));
      *(bf16x2*)(Pb + idx) = out;
      sk0  = fmaf(d0, sk0, k0);   skv0 = fmaf(d0, skv0, kv0);
      sk1  = fmaf(d1, sk1, k1);   skv1 = fmaf(d1, skv1, kv1);
    }
  }
}

// ---------------- MFMA GEMM core (BK=64, bank-conflict phase swizzle) ----------------
__device__ __forceinline__ void gld_lds(const bf16* g, bf16* l) {
  __builtin_amdgcn_global_load_lds(
      (const __attribute__((address_space(1))) void*)(g),
      (__attribute__((address_space(3))) void*)(l),
      16, 0, 0);
}

// XCD-aware swizzle: xcd=s%8 owns m-band; n in groups of 2, m fastest.
__device__ __forceinline__ void swz(int s, int gm, int& m_t, int& n_t) {
  const int mpx  = gm >> 3;        // gm % 8 == 0 at all call sites
  const int xcd  = s & 7;
  const int ss   = s >> 3;
  const int pass = mpx << 1;
  const int ng   = ss / pass;
  const int rem  = ss - ng * pass;
  m_t = xcd * mpx + (rem >> 1);
  n_t = (ng << 1) + (rem & 1);
}

__device__ __forceinline__ void mm_core64(
    const bf16* A, const bf16* Bt, int lda, int ldb, int K,
    long m0, long n0, int wv, int lane, int wm, int wn,
    bf16* As, bf16* Bs, floatx4 acc[4][4]) {
  const int srow = wv * 32 + (lane >> 2);
  // phase swizzle: physical slot lane&3 holds logical group (slot - (srow>>1)) & 3
  const int scol = (((lane & 3) - ((lane >> 3) & 3)) & 3) * 8;
  const bf16* gA = A + (m0 + srow) * (long)lda + scol;
  const bf16* gB = Bt + (n0 + srow) * (long)ldb + scol;
  const long skipA = 16L * lda;
  const long skipB = 16L * ldb;
  bf16* lA = As + wv * 1024;
  bf16* lB = Bs + wv * 1024;
  const int pg = ((lane >> 4) + ((lane >> 1) & 3)) & 3;
  const bf16* fa = As + ((wm * 64) + (lane & 15)) * 32 + pg * 8;
  const bf16* fb = Bs + ((wn * 64) + (lane & 15)) * 32 + pg * 8;

  const int ksteps = K >> 6;
  for (int kt = 0; kt < ksteps; ++kt) {
    __syncthreads();
    gld_lds(gA, lA);             gld_lds(gA + skipA, lA + 512);
    gld_lds(gA + 32, lA + 4096); gld_lds(gA + 32 + skipA, lA + 4096 + 512);
    gld_lds(gB, lB);             gld_lds(gB + skipB, lB + 512);
    gld_lds(gB + 32, lB + 4096); gld_lds(gB + 32 + skipB, lB + 4096 + 512);
    gA += 64; gB += 64;
    __syncthreads();
#pragma unroll
    for (int s = 0; s < 2; s++) {
      bf16x8 af[4], bfr[4];
#pragma unroll
      for (int i = 0; i < 4; i++) {
        af[i]  = *(const bf16x8*)(fa + s * 4096 + i * 512);
        bfr[i] = *(const bf16x8*)(fb + s * 4096 + i * 512);
      }
#pragma unroll
      for (int mt = 0; mt < 4; mt++)
#pragma unroll
        for (int nt = 0; nt < 4; nt++)
          acc[mt][nt] = __builtin_amdgcn_mfma_f32_16x16x32_bf16(af[mt], bfr[nt], acc[mt][nt], 0, 0, 0);
    }
  }
}

enum { E_EXP = 0, E_BF16 = 1, E_SIG = 2, E_ADD1 = 3, E_SILU = 4, E_F32 = 5, E_SIGADD2 = 6 };

template <int EPI>
__device__ __forceinline__ void epilogue(
    floatx4 acc[4][4], void* Cout, const void* aux1, const void* aux2,
    long m0, long n0, int ldc, int lane, int wm, int wn) {
  const int r0 = wm * 64 + ((lane >> 4) << 2);
  const int c0 = wn * 64 + (lane & 15);
#pragma unroll
  for (int mt = 0; mt < 4; mt++) {
#pragma unroll
    for (int i = 0; i < 4; i++) {
      long r = m0 + r0 + mt * 16 + i;
      long bidx = r * (long)ldc + n0 + c0;
#pragma unroll
      for (int nt = 0; nt < 4; nt++) {
        long idx = bidx + nt * 16;
        float v = acc[mt][nt][i];
        if constexpr (EPI == E_EXP) {
          ((bf16*)Cout)[idx] = f2bf(__expf(fminf(v, 60.f)));
        } else if constexpr (EPI == E_BF16) {
          ((bf16*)Cout)[idx] = f2bf(v);
        } else if constexpr (EPI == E_SIG) {
          ((bf16*)Cout)[idx] = f2bf(1.f / (1.f + __expf(-v)));
        } else if constexpr (EPI == E_ADD1) {
          float prev = ((const float*)aux1)[idx];   // may alias Cout (same idx)
          ((float*)Cout)[idx] = v + prev;
        } else if constexpr (EPI == E_SILU) {
          ((bf16*)Cout)[idx] = f2bf(v / (1.f + __expf(-v)));
        } else if constexpr (EPI == E_F32) {
          ((float*)Cout)[idx] = v;
        } else {  // E_SIGADD2
          float a1 = ((const float*)aux1)[idx];
          float a2 = ((const float*)aux2)[idx];
          ((float*)Cout)[idx] = a1 + 1.f / (1.f + __expf(-v)) + a2;
        }
      }
    }
  }
}

// MT = M-tiles per block (serial, shared B n-tile). gm counts super-tiles of 128*MT rows.
template <int EPI, int MT>
__global__ __launch_bounds__(256) void gemm_bt(
    const bf16* __restrict__ A, const bf16* __restrict__ Bt,
    void* Cout, const void* aux1, const void* aux2,
    int lda, int ldb, int ldc, int K, int gm, int gn) {
  __shared__ __align__(16) bf16 As[2 * 128 * 32];
  __shared__ __align__(16) bf16 Bs[2 * 128 * 32];
  const int tid = threadIdx.x;
  const int lane = tid & 63;
  const int wv = tid >> 6;
  const int wm = wv >> 1, wn = wv & 1;
  int m_t, n_t;
  swz(blockIdx.x, gm, m_t, n_t);
  const long n0 = (long)n_t * 128;

#pragma unroll
  for (int sm = 0; sm < MT; sm++) {
    const long m0 = (long)m_t * (128 * MT) + sm * 128;
    floatx4 acc[4][4];
#pragma unroll
    for (int i = 0; i < 4; i++)
#pragma unroll
      for (int j = 0; j < 4; j++) acc[i][j] = (floatx4){0.f, 0.f, 0.f, 0.f};
    mm_core64(A, Bt, lda, ldb, K, m0, n0, wv, lane, wm, wn, As, Bs, acc);
    epilogue<EPI>(acc, Cout, aux1, aux2, m0, n0, ldc, lane, wm, wn);
  }
}

// ---------------- fused K/V/R projection: 3 GEMMs, 2 m-tiles/block ----------------
// grid = 3 * gm * gn where gm counts 256-row super-tiles (gm = M/256).
__global__ __launch_bounds__(256) void proj3(
    const bf16* __restrict__ xk, const bf16* __restrict__ xv, const bf16* __restrict__ xr,
    const bf16* __restrict__ Wk, const bf16* __restrict__ Wv, const bf16* __restrict__ Wr,
    bf16* Kc, bf16* Vc, bf16* SRc, int gm, int gn) {
  __shared__ __align__(16) bf16 As[2 * 128 * 32];
  __shared__ __align__(16) bf16 Bs[2 * 128 * 32];
  const int per = gm * gn;
  const int sub = blockIdx.x / per;          // 0:K 1:V 2:R
  const int s   = blockIdx.x - sub * per;
  const int tid = threadIdx.x;
  const int lane = tid & 63;
  const int wv = tid >> 6;
  const int wm = wv >> 1, wn = wv & 1;
  int m_t, n_t;
  swz(s, gm, m_t, n_t);
  const long n0 = (long)n_t * 128;

  const bf16* A  = (sub == 0) ? xk : (sub == 1) ? xv : xr;
  const bf16* Bt = (sub == 0) ? Wk : (sub == 1) ? Wv : Wr;
  bf16*       C  = (sub == 0) ? Kc : (sub == 1) ? Vc : SRc;

#pragma unroll
  for (int sm = 0; sm < 2; sm++) {
    const long m0 = (long)m_t * 256 + sm * 128;
    floatx4 acc[4][4];
#pragma unroll
    for (int i = 0; i < 4; i++)
#pragma unroll
      for (int j = 0; j < 4; j++) acc[i][j] = (floatx4){0.f, 0.f, 0.f, 0.f};
    mm_core64(A, Bt, Hdim, Hdim, Hdim, m0, n0, wv, lane, wm, wn, As, Bs, acc);

    const int r0 = wm * 64 + ((lane >> 4) << 2);
    const int c0 = wn * 64 + (lane & 15);
#pragma unroll
    for (int mt = 0; mt < 4; mt++) {
#pragma unroll
      for (int i = 0; i < 4; i++) {
        long r = m0 + r0 + mt * 16 + i;
        long bidx = r * (long)CHUNK + n0 + c0;
#pragma unroll
        for (int nt = 0; nt < 4; nt++) {
          long idx = bidx + nt * 16;
          float v = acc[mt][nt][i];
          float o;
          if (sub == 0)      o = __expf(fminf(v, 60.f));
          else if (sub == 1) o = v;
          else               o = 1.f / (1.f + __expf(-v));
          C[idx] = f2bf(o);
        }
      }
    }
  }
}

// ---------------- launch ----------------
extern "C" void kernel_launch(void* const* d_in, const int* in_sizes, int n_in,
                              void* d_out, int out_size, void* d_ws, size_t ws_size,
                              hipStream_t stream) {
  (void)in_sizes; (void)n_in; (void)out_size; (void)ws_size;
  const float* x        = (const float*)d_in[0];
  const float* ln0_g    = (const float*)d_in[1];
  const float* ln0_b    = (const float*)d_in[2];
  const float* pre_g    = (const float*)d_in[3];
  const float* pre_b    = (const float*)d_in[4];
  const float* post_g   = (const float*)d_in[5];
  const float* post_b   = (const float*)d_in[6];
  const float* tm_decay = (const float*)d_in[7];
  const float* tm_first = (const float*)d_in[8];
  const float* tm_mix_k = (const float*)d_in[9];
  const float* tm_mix_v = (const float*)d_in[10];
  const float* tm_mix_r = (const float*)d_in[11];
  const float* tm_Wk    = (const float*)d_in[12];
  const float* tm_Wv    = (const float*)d_in[13];
  const float* tm_Wr    = (const float*)d_in[14];
  const float* tm_Wo    = (const float*)d_in[15];
  const float* cm_mix_k = (const float*)d_in[16];
  const float* cm_mix_r = (const float*)d_in[17];
  const float* cm_Wk    = (const float*)d_in[18];
  const float* cm_Wv    = (const float*)d_in[19];
  const float* cm_Wr    = (const float*)d_in[20];

  char* ws = (char*)d_ws;
  // static layout (bytes); peak 238,026,752 (227 MiB)
  bf16*  WkT  = (bf16*)(ws + 0);          // [HU,H]
  bf16*  WvT  = (bf16*)(ws + 8388608);    // [HU,H]
  bf16*  WrT  = (bf16*)(ws + 16777216);   // [HU,H]
  bf16*  WoT  = (bf16*)(ws + 25165824);   // [H,HU]
  bf16*  cWkT = (bf16*)(ws + 33554432);   // [HU,H]
  bf16*  cWvT = (bf16*)(ws + 41943040);   // [H,HU]
  bf16*  cWrT = (bf16*)(ws + 50331648);   // [H,H]
  float* xres = (float*)(ws + 52428800);  // [M,H] f32
  bf16*  xk   = (bf16*)(ws + 85983232);   // [M,H]
  bf16*  xv   = (bf16*)(ws + 102760448);
  bf16*  xr   = (bf16*)(ws + 119537664);
  bf16*  Kc   = (bf16*)(ws + 136314880);  // [M,CHUNK]
  bf16*  Vc   = (bf16*)(ws + 169869312);  // [M,CHUNK]
  bf16*  SRc  = (bf16*)(ws + 203423744);  // [M,CHUNK], P written in place
  float* stK  = (float*)(ws + 236978176); // [NSEG,B,CHUNK] f32 (512 KiB)
  float* stKV = (float*)(ws + 237502464); // [NSEG,B,CHUNK] f32 (512 KiB)
  // CM-phase aliases (regions dead by then):
  bf16*  xk2  = (bf16*)(ws + 136314880);  // over Kc
  bf16*  xr2  = (bf16*)(ws + 153092096);  // over Kc (2nd half)
  bf16*  hbuf = (bf16*)(ws + 169869312);  // [M,HU] over Vc+SRc
  float* hv   = (float*)(ws + 85983232);  // [M,H] f32 over xk+xv

  dim3 blk(256);
  wconv_all<<<6400, blk, 0, stream>>>(tm_Wk, tm_Wv, tm_Wr, tm_Wo, cm_Wk, cm_Wv, cm_Wr,
                                      WkT, WvT, WrT, WoT, cWkT, cWvT, cWrT);

  ln_mix_tm<<<Mrows, blk, 0, stream>>>(x, ln0_g, ln0_b, pre_g, pre_b,
                                       tm_mix_k, tm_mix_v, tm_mix_r, xres, xk, xv, xr);

  const int scan_grid = NSEG * Bdim * (CHUNK / 128);  // 1024 blocks
  const int GM = Mrows / 128;                          // 64
  const int GM2 = Mrows / 256;                         // 32 (2 m-tiles/block)
  const int GNp = CHUNK / 128;                         // 16
  for (int ch = 0; ch < NCH; ch++) {
    const long woff = (long)ch * CHUNK;
    proj3<<<3 * GM2 * GNp, blk, 0, stream>>>(           // 1536 tiles in 768 blocks
        xk, xv, xr, WkT + woff * Hdim, WvT + woff * Hdim, WrT + woff * Hdim,
        Kc, Vc, SRc, GM2, GNp);

    wkv_part<<<scan_grid, dim3(64), 0, stream>>>(
        Kc, Vc, stK, stKV, tm_decay + woff);
    wkv_emit<<<scan_grid, dim3(64), 0, stream>>>(
        Kc, Vc, SRc, SRc, stK, stKV, tm_decay + woff, tm_first + woff);

    // xres += P_ch @ Wo[ch*CHUNK:,:]
    gemm_bt<E_ADD1, 1><<<GM * (Hdim/128), blk, 0, stream>>>(
        SRc, WoT + woff, xres, xres, nullptr, CHUNK, HUdim, Hdim, CHUNK, GM, Hdim/128);
  }

  ln_mix_cm<<<Mrows, blk, 0, stream>>>(xres, post_g, post_b, cm_mix_k, cm_mix_r, xk2, xr2);

  // hbuf = silu(xk2 @ cWk) over full HU; 2 m-tiles/block -> 1024 blocks
  gemm_bt<E_SILU, 2><<<GM2 * (HUdim/128), blk, 0, stream>>>(
      xk2, cWkT, hbuf, nullptr, nullptr, Hdim, Hdim, HUdim, Hdim, GM2, HUdim/128);

  // hv = hbuf @ cWv (K=4096) as two chained K=2048 halves
  gemm_bt<E_F32, 1><<<GM * (Hdim/128), blk, 0, stream>>>(
      hbuf, cWvT, hv, nullptr, nullptr, HUdim, HUdim, Hdim, CHUNK, GM, Hdim/128);
  gemm_bt<E_ADD1, 1><<<GM * (Hdim/128), blk, 0, stream>>>(
      hbuf + CHUNK, cWvT + CHUNK, hv, hv, nullptr, HUdim, HUdim, Hdim, CHUNK, GM, Hdim/128);

  gemm_bt<E_SIGADD2, 1><<<GM * (Hdim/128), blk, 0, stream>>>(
      xr2, cWrT, (float*)d_out, xres, hv, Hdim, Hdim, Hdim, Hdim, GM, Hdim/128);
}